// Round 9
// baseline (1404.699 us; speedup 1.0000x reference)
//
#include <hip/hip_runtime.h>
#include <hip/hip_bf16.h>

#define NN 100000
#define NE 1600000
#define DD 128
#define DFF 256
#define BN_EPS 1e-5f
#define NND ((size_t)NN * DD)
#define NTILE 6250   // NN/16
#define GA 512       // megaA grid
#define GB 512       // megaB grid
#define TR1 136      // padded LDS row stride (elems) for 128-wide transpose
#define TR2 264      // padded LDS row stride (elems) for 256-wide transpose

typedef __attribute__((ext_vector_type(8))) short short8;
typedef __attribute__((ext_vector_type(4))) float f32x4;
typedef __attribute__((ext_vector_type(4))) unsigned short us4;

static __device__ __forceinline__ unsigned short f2bf(float f) {
  union { float f; unsigned u; } v; v.f = f;
  unsigned r = v.u + 0x7fffu + ((v.u >> 16) & 1u);
  return (unsigned short)(r >> 16);
}
static __device__ __forceinline__ float bf2f(unsigned short h) {
  union { unsigned u; float f; } v; v.u = ((unsigned)h) << 16;
  return v.f;
}

// ---- device-wide barrier: counter starts 0 (memset in graph), ends at nblk --
static __device__ __forceinline__ void gsync(int* cnt, int nblk) {
  __syncthreads();
  if (threadIdx.x == 0) {
    __threadfence();
    __hip_atomic_fetch_add(cnt, 1, __ATOMIC_ACQ_REL, __HIP_MEMORY_SCOPE_AGENT);
    while (__hip_atomic_load(cnt, __ATOMIC_ACQUIRE, __HIP_MEMORY_SCOPE_AGENT) < nblk)
      __builtin_amdgcn_s_sleep(8);
    __threadfence();
  }
  __syncthreads();
}

// ================= megaA: zero + prep + hist + scan + scatter ================
__global__ __launch_bounds__(256, 2) void k_megaA(
    const float* __restrict__ x, unsigned short* __restrict__ xbf,
    const float* __restrict__ w1g, const float* __restrict__ w2g,
    const float* __restrict__ ffw1, const float* __restrict__ ffw2,
    unsigned short* __restrict__ w1t, unsigned short* __restrict__ w2t,
    unsigned short* __restrict__ fw1t, unsigned short* __restrict__ fw2t,
    const int* __restrict__ ei, int* __restrict__ rs, int* __restrict__ cursor,
    int* __restrict__ bsum, int* __restrict__ bpre, float* __restrict__ stats,
    int2* __restrict__ el2, int* bar) {
  __shared__ int sh[256];
  int blk = blockIdx.x, t = threadIdx.x;
  int gid = blk * 256 + t;                     // [0, 131072)
  const int NT = GA * 256;

  // P0: zero rs[0..NN] and stats[0..511]
  for (int i = gid; i <= NN; i += NT) rs[i] = 0;
  if (gid < 512) stats[gid] = 0.f;
  gsync(bar + 0, GA);

  // P1: xbf = bf16(x); transposed bf16 weights; histogram
  for (int i = gid; i < 1600000; i += NT) {    // 12.8M elems / 8
    size_t base = (size_t)i * 8;
    const f32x4* xp = reinterpret_cast<const f32x4*>(x + base);
    f32x4 a0 = xp[0], a1 = xp[1];
    short8 o;
#pragma unroll
    for (int j = 0; j < 4; ++j) o[j] = (short)f2bf(a0[j]);
#pragma unroll
    for (int j = 0; j < 4; ++j) o[4 + j] = (short)f2bf(a1[j]);
    *reinterpret_cast<short8*>(xbf + base) = o;
  }
  for (int i = gid; i < 98304; i += NT) {
    int ii = i;
    if (ii < 16384) { int c = ii & 127, k = ii >> 7; w1t[c * 128 + k] = f2bf(w1g[k * 128 + c]); }
    else if (ii < 32768) { ii -= 16384; int c = ii & 127, k = ii >> 7; w2t[c * 128 + k] = f2bf(w2g[k * 128 + c]); }
    else if (ii < 65536) { ii -= 32768; int c = ii & 255, k = ii >> 8; fw1t[c * 128 + k] = f2bf(ffw1[k * 256 + c]); }
    else { ii -= 65536; int c = ii & 127, k = ii >> 7; fw2t[c * 256 + k] = f2bf(ffw2[k * 128 + c]); }
  }
  for (int e = gid; e < NE; e += NT) atomicAdd(&rs[ei[NE + e]], 1);
  gsync(bar + 1, GA);

  // P2: per-block inclusive scan of rs (one element per thread; 131072 >= NN)
  int v = (gid < NN) ? rs[gid] : 0;
  sh[t] = v;
  __syncthreads();
  for (int off = 1; off < 256; off <<= 1) {
    int u = (t >= off) ? sh[t - off] : 0;
    __syncthreads();
    sh[t] += u;
    __syncthreads();
  }
  int incl = sh[t];
  int ex = incl - v;
  if (t == 255) bsum[blk] = incl;
  gsync(bar + 2, GA);

  // P3: block 0 exclusive-scans bsum[512] -> bpre; total -> rs[NN]
  if (blk == 0) {
    int a0 = bsum[2 * t], a1 = bsum[2 * t + 1];
    int ps = a0 + a1;
    sh[t] = ps;
    __syncthreads();
    for (int off = 1; off < 256; off <<= 1) {
      int u = (t >= off) ? sh[t - off] : 0;
      __syncthreads();
      sh[t] += u;
      __syncthreads();
    }
    int excl = sh[t] - ps;
    bpre[2 * t] = excl;
    bpre[2 * t + 1] = excl + a0;
    if (t == 255) rs[NN] = sh[255];
  }
  gsync(bar + 3, GA);

  // P4: finalize exclusive prefix + cursor init
  if (gid < NN) {
    int e0 = bpre[blk] + ex;
    rs[gid] = e0;
    cursor[gid] = e0;
  }
  gsync(bar + 4, GA);

  // P5: scatter (edge, src) into dst-sorted order
  for (int e = gid; e < NE; e += NT) {
    int s = ei[e], d = ei[NE + e];
    int p = atomicAdd(&cursor[d], 1);
    el2[p] = make_int2(e, s);
  }
}

// ---- gather (R5 shape): 32 lanes/node, 4-deep pipeline, bf16 x --------------
__global__ __launch_bounds__(256) void k_gather(
    const unsigned short* __restrict__ xbf, const float* __restrict__ ea,
    const int* __restrict__ rs, const int2* __restrict__ el2,
    unsigned short* __restrict__ h0) {
  int n = blockIdx.x * 8 + (threadIdx.x >> 5);
  int q = threadIdx.x & 31;
  int beg = rs[n], end = rs[n + 1];
  f32x4 acc = (f32x4){0.f, 0.f, 0.f, 0.f};
  int2 E0 = make_int2(0, 0), E1 = E0, E2 = E0, E3 = E0;
  int i = beg;
  if (i     < end) E0 = el2[i];
  if (i + 1 < end) E1 = el2[i + 1];
  if (i + 2 < end) E2 = el2[i + 2];
  if (i + 3 < end) E3 = el2[i + 3];
  for (; i + 4 <= end; i += 4) {
    f32x4 ev0 = *(reinterpret_cast<const f32x4*>(ea + (size_t)E0.x * DD) + q);
    us4  xv0 = *reinterpret_cast<const us4*>(xbf + (size_t)E0.y * DD + q * 4);
    f32x4 ev1 = *(reinterpret_cast<const f32x4*>(ea + (size_t)E1.x * DD) + q);
    us4  xv1 = *reinterpret_cast<const us4*>(xbf + (size_t)E1.y * DD + q * 4);
    f32x4 ev2 = *(reinterpret_cast<const f32x4*>(ea + (size_t)E2.x * DD) + q);
    us4  xv2 = *reinterpret_cast<const us4*>(xbf + (size_t)E2.y * DD + q * 4);
    f32x4 ev3 = *(reinterpret_cast<const f32x4*>(ea + (size_t)E3.x * DD) + q);
    us4  xv3 = *reinterpret_cast<const us4*>(xbf + (size_t)E3.y * DD + q * 4);
    int2 N0 = E0, N1 = E1, N2 = E2, N3 = E3;
    if (i + 4 < end) N0 = el2[i + 4];
    if (i + 5 < end) N1 = el2[i + 5];
    if (i + 6 < end) N2 = el2[i + 6];
    if (i + 7 < end) N3 = el2[i + 7];
#pragma unroll
    for (int c = 0; c < 4; ++c) {
      float m0 = bf2f((unsigned short)xv0[c]) + ev0[c];
      acc[c] += (m0 > 0.f) ? m0 : 0.f;
      float m1 = bf2f((unsigned short)xv1[c]) + ev1[c];
      acc[c] += (m1 > 0.f) ? m1 : 0.f;
      float m2 = bf2f((unsigned short)xv2[c]) + ev2[c];
      acc[c] += (m2 > 0.f) ? m2 : 0.f;
      float m3 = bf2f((unsigned short)xv3[c]) + ev3[c];
      acc[c] += (m3 > 0.f) ? m3 : 0.f;
    }
    E0 = N0; E1 = N1; E2 = N2; E3 = N3;
  }
  if (i < end) {
    f32x4 ev = *(reinterpret_cast<const f32x4*>(ea + (size_t)E0.x * DD) + q);
    us4  xv = *reinterpret_cast<const us4*>(xbf + (size_t)E0.y * DD + q * 4);
#pragma unroll
    for (int c = 0; c < 4; ++c) {
      float m = bf2f((unsigned short)xv[c]) + ev[c];
      acc[c] += (m > 0.f) ? m : 0.f;
    }
  }
  if (i + 1 < end) {
    f32x4 ev = *(reinterpret_cast<const f32x4*>(ea + (size_t)E1.x * DD) + q);
    us4  xv = *reinterpret_cast<const us4*>(xbf + (size_t)E1.y * DD + q * 4);
#pragma unroll
    for (int c = 0; c < 4; ++c) {
      float m = bf2f((unsigned short)xv[c]) + ev[c];
      acc[c] += (m > 0.f) ? m : 0.f;
    }
  }
  if (i + 2 < end) {
    f32x4 ev = *(reinterpret_cast<const f32x4*>(ea + (size_t)E2.x * DD) + q);
    us4  xv = *reinterpret_cast<const us4*>(xbf + (size_t)E2.y * DD + q * 4);
#pragma unroll
    for (int c = 0; c < 4; ++c) {
      float m = bf2f((unsigned short)xv[c]) + ev[c];
      acc[c] += (m > 0.f) ? m : 0.f;
    }
  }
  us4 xs = *reinterpret_cast<const us4*>(xbf + (size_t)n * DD + q * 4);
  union { unsigned short us[4]; unsigned long long u; } pk;
#pragma unroll
  for (int c = 0; c < 4; ++c) pk.us[c] = f2bf(bf2f((unsigned short)xs[c]) + acc[c]);
  *reinterpret_cast<unsigned long long*>(h0 + (size_t)n * DD + q * 4) = pk.u;
}

// ======= megaB: mlp1(+BN1 stats) | sync | bn1fin | mlp2(+BN2 stats) | sync |
//         bn2 apply — all one launch ========================================
__global__ __launch_bounds__(256, 2) void k_megaB(
    const unsigned short* __restrict__ hbf,
    const unsigned short* __restrict__ W1T, const float* __restrict__ b1,
    const unsigned short* __restrict__ W2T, const float* __restrict__ b2,
    const unsigned short* __restrict__ xbf, float* __restrict__ O,
    float* __restrict__ stats,
    const float* __restrict__ bn1g, const float* __restrict__ bn1b,
    const unsigned short* __restrict__ FW1T, const float* __restrict__ fb1,
    const unsigned short* __restrict__ FW2T, const float* __restrict__ fb2,
    const float* __restrict__ bn2g, const float* __restrict__ bn2b, int* bar) {
  __shared__ unsigned short trb[4][16 * TR2];   // 33.8KB; mlp1 uses TR1 stride
  __shared__ float lds_s[128], lds_q[128], ldspar[256];
  int t = threadIdx.x;
  int lane = t & 63, w = t >> 6;
  int l15 = lane & 15, g = lane >> 4;
  int wid = blockIdx.x * 4 + w;                // [0, 2048)
  if (t < 128) { lds_s[t] = 0.f; lds_q[t] = 0.f; }
  __syncthreads();

  // ---- phase mlp1: out = x + relu(relu(h0@W1+b1)@W2+b2), BN1 stats ----------
  for (int tile = wid; tile < NTILE; tile += GB * 4) {
    int row0 = tile * 16;
    f32x4 acc[8];
#pragma unroll
    for (int ct = 0; ct < 8; ++ct) { float b = b1[ct * 16 + l15]; acc[ct] = (f32x4){b, b, b, b}; }
    short8 a[4];
#pragma unroll
    for (int kt = 0; kt < 4; ++kt)
      a[kt] = *reinterpret_cast<const short8*>(hbf + (size_t)(row0 + l15) * DD + kt * 32 + g * 8);
#pragma unroll
    for (int kt = 0; kt < 4; ++kt) {
      int k0 = kt * 32 + g * 8;
#pragma unroll
      for (int ct = 0; ct < 8; ++ct) {
        int c = ct * 16 + l15;
        short8 b = *reinterpret_cast<const short8*>(W1T + (size_t)c * DD + k0);
        acc[ct] = __builtin_amdgcn_mfma_f32_16x16x32_bf16(a[kt], b, acc[ct], 0, 0, 0);
      }
    }
#pragma unroll
    for (int ct = 0; ct < 8; ++ct)
#pragma unroll
      for (int r = 0; r < 4; ++r) {
        float v = acc[ct][r];
        v = v > 0.f ? v : 0.f;
        trb[w][(g * 4 + r) * TR1 + ct * 16 + l15] = f2bf(v);
      }
    // same-wave LDS read-back (no barrier needed)
    short8 a2[4];
#pragma unroll
    for (int kt = 0; kt < 4; ++kt)
      a2[kt] = *reinterpret_cast<const short8*>(&trb[w][l15 * TR1 + kt * 32 + g * 8]);
    f32x4 acc2[8];
#pragma unroll
    for (int ct = 0; ct < 8; ++ct) { float b = b2[ct * 16 + l15]; acc2[ct] = (f32x4){b, b, b, b}; }
#pragma unroll
    for (int kt = 0; kt < 4; ++kt) {
      int k0 = kt * 32 + g * 8;
#pragma unroll
      for (int ct = 0; ct < 8; ++ct) {
        int c = ct * 16 + l15;
        short8 b = *reinterpret_cast<const short8*>(W2T + (size_t)c * DD + k0);
        acc2[ct] = __builtin_amdgcn_mfma_f32_16x16x32_bf16(a2[kt], b, acc2[ct], 0, 0, 0);
      }
    }
#pragma unroll
    for (int ct = 0; ct < 8; ++ct) {
      int c = ct * 16 + l15;
      float s = 0.f, q = 0.f;
#pragma unroll
      for (int r = 0; r < 4; ++r) {
        int row = row0 + g * 4 + r;
        float v = acc2[ct][r];
        v = v > 0.f ? v : 0.f;
        v += bf2f(xbf[(size_t)row * DD + c]);
        O[(size_t)row * DD + c] = v;
        s += v; q += v * v;
      }
      s += __shfl_xor(s, 16); s += __shfl_xor(s, 32);
      q += __shfl_xor(q, 16); q += __shfl_xor(q, 32);
      if (g == 0) { atomicAdd(&lds_s[c], s); atomicAdd(&lds_q[c], q); }
    }
  }
  __syncthreads();
  if (t < 128) {
    atomicAdd(&stats[t], lds_s[t]);
    atomicAdd(&stats[128 + t], lds_q[t]);
    lds_s[t] = 0.f; lds_q[t] = 0.f;   // re-zero for BN2 stats
  }
  gsync(bar + 5, GB);

  // ---- BN1 finalize, per block (redundant, cheap) ---------------------------
  if (t < 128) {
    float mean = stats[t] * (1.f / NN);
    float var = stats[128 + t] * (1.f / NN) - mean * mean;
    float sc = bn1g[t] * rsqrtf(var + BN_EPS);
    ldspar[t] = sc;
    ldspar[128 + t] = bn1b[t] - mean * sc;
  }
  __syncthreads();

  // ---- phase mlp2: out = bn1(out) + relu(bn1(out)@FW1+fb1)@FW2+fb2 ----------
  for (int tile = wid; tile < NTILE; tile += GB * 4) {
    int row0 = tile * 16;
    const float* arow = O + (size_t)(row0 + l15) * DD;
    short8 a1[4];
#pragma unroll
    for (int kt = 0; kt < 4; ++kt) {
      int k0 = kt * 32 + g * 8;
      f32x4 u0 = *reinterpret_cast<const f32x4*>(arow + k0);
      f32x4 u1 = *reinterpret_cast<const f32x4*>(arow + k0 + 4);
      short8 af;
#pragma unroll
      for (int j = 0; j < 4; ++j)
        af[j] = (short)f2bf(ldspar[k0 + j] * u0[j] + ldspar[128 + k0 + j]);
#pragma unroll
      for (int j = 0; j < 4; ++j)
        af[4 + j] = (short)f2bf(ldspar[k0 + 4 + j] * u1[j] + ldspar[128 + k0 + 4 + j]);
      a1[kt] = af;
    }
    f32x4 acc1[16];
#pragma unroll
    for (int ct = 0; ct < 16; ++ct) { float b = fb1[ct * 16 + l15]; acc1[ct] = (f32x4){b, b, b, b}; }
#pragma unroll
    for (int kt = 0; kt < 4; ++kt) {
      int k0 = kt * 32 + g * 8;
#pragma unroll
      for (int ct = 0; ct < 16; ++ct) {
        int c = ct * 16 + l15;
        short8 b = *reinterpret_cast<const short8*>(FW1T + (size_t)c * DD + k0);
        acc1[ct] = __builtin_amdgcn_mfma_f32_16x16x32_bf16(a1[kt], b, acc1[ct], 0, 0, 0);
      }
    }
#pragma unroll
    for (int ct = 0; ct < 16; ++ct)
#pragma unroll
      for (int r = 0; r < 4; ++r) {
        float v = acc1[ct][r];
        v = v > 0.f ? v : 0.f;
        trb[w][(g * 4 + r) * TR2 + ct * 16 + l15] = f2bf(v);
      }
    short8 a2[8];
#pragma unroll
    for (int kt = 0; kt < 8; ++kt)
      a2[kt] = *reinterpret_cast<const short8*>(&trb[w][l15 * TR2 + kt * 32 + g * 8]);
    f32x4 acc2[8];
#pragma unroll
    for (int ct = 0; ct < 8; ++ct) { float b = fb2[ct * 16 + l15]; acc2[ct] = (f32x4){b, b, b, b}; }
#pragma unroll 2
    for (int kt = 0; kt < 8; ++kt) {
      int k0 = kt * 32 + g * 8;
#pragma unroll
      for (int ct = 0; ct < 8; ++ct) {
        int c = ct * 16 + l15;
        short8 b = *reinterpret_cast<const short8*>(FW2T + (size_t)c * DFF + k0);
        acc2[ct] = __builtin_amdgcn_mfma_f32_16x16x32_bf16(a2[kt], b, acc2[ct], 0, 0, 0);
      }
    }
#pragma unroll
    for (int ct = 0; ct < 8; ++ct) {
      int c = ct * 16 + l15;
      float sc = ldspar[c], shv = ldspar[128 + c];
      float s = 0.f, q = 0.f;
#pragma unroll
      for (int r = 0; r < 4; ++r) {
        int row = row0 + g * 4 + r;
        float h1v = sc * O[(size_t)row * DD + c] + shv;
        float v = acc2[ct][r] + h1v;
        O[(size_t)row * DD + c] = v;
        s += v; q += v * v;
      }
      s += __shfl_xor(s, 16); s += __shfl_xor(s, 32);
      q += __shfl_xor(q, 16); q += __shfl_xor(q, 32);
      if (g == 0) { atomicAdd(&lds_s[c], s); atomicAdd(&lds_q[c], q); }
    }
  }
  __syncthreads();
  if (t < 128) {
    atomicAdd(&stats[256 + t], lds_s[t]);
    atomicAdd(&stats[384 + t], lds_q[t]);
  }
  gsync(bar + 6, GB);

  // ---- phase bn2 apply: out = bn2(out) --------------------------------------
  {
    int gid = blockIdx.x * 256 + t;      // f32x4 group index base, stride 131072
    int cb = (gid & 31) * 4;             // stride % 32 == 0 -> channel set fixed
    f32x4 sc4, sh4;
#pragma unroll
    for (int j = 0; j < 4; ++j) {
      int c = cb + j;
      float mean = stats[256 + c] * (1.f / NN);
      float var = stats[384 + c] * (1.f / NN) - mean * mean;
      float sc = bn2g[c] * rsqrtf(var + BN_EPS);
      sc4[j] = sc;
      sh4[j] = bn2b[c] - mean * sc;
    }
    for (int idx = gid; idx < 3200000; idx += GB * 256) {
      f32x4* p = reinterpret_cast<f32x4*>(O + (size_t)idx * 4);
      f32x4 v = *p;
#pragma unroll
      for (int j = 0; j < 4; ++j) v[j] = sc4[j] * v[j] + sh4[j];
      *p = v;
    }
  }
}

extern "C" void kernel_launch(void* const* d_in, const int* in_sizes, int n_in,
                              void* d_out, int out_size, void* d_ws, size_t ws_size,
                              hipStream_t stream) {
  const float* x    = (const float*)d_in[0];
  const float* ea   = (const float*)d_in[1];
  const float* w1g  = (const float*)d_in[2];
  const float* b1g  = (const float*)d_in[3];
  const float* w2g  = (const float*)d_in[4];
  const float* b2g  = (const float*)d_in[5];
  const float* bn1g = (const float*)d_in[6];
  const float* bn1b = (const float*)d_in[7];
  const float* ffw1 = (const float*)d_in[8];
  const float* ffb1 = (const float*)d_in[9];
  const float* ffw2 = (const float*)d_in[10];
  const float* ffb2 = (const float*)d_in[11];
  const float* bn2g = (const float*)d_in[12];
  const float* bn2b = (const float*)d_in[13];
  const int*   eidx = (const int*)d_in[14];
  float* out = (float*)d_out;

  char* ws = (char*)d_ws;
  int2* el2    = (int2*)(ws);                          // 12.8 MB
  int*  rs     = (int*)(ws + 12800000);                // NN+1 ints
  int*  cursor = (int*)(ws + 13200128);                // NN ints
  int*  bsum   = (int*)(ws + 13600128);                // 512 ints
  int*  bpre   = (int*)(ws + 13602176);                // 512 ints
  float* stats = (float*)(ws + 13604224);              // 512 f32 (BN1+BN2)
  int*  bar    = (int*)(ws + 13606272);                // 16 ints (7 used)
  unsigned short* w1t  = (unsigned short*)(ws + 13606400);
  unsigned short* w2t  = (unsigned short*)(ws + 13639168);
  unsigned short* fw1t = (unsigned short*)(ws + 13671936);
  unsigned short* fw2t = (unsigned short*)(ws + 13737472);
  unsigned short* xbf  = (unsigned short*)(ws + 13803008);  // 25.6 MB
  unsigned short* hbf  = (unsigned short*)(ws + 39403008);  // 25.6 MB

  hipMemsetAsync(bar, 0, 64, stream);   // self-contained barrier state per replay

  k_megaA<<<GA, 256, 0, stream>>>(x, xbf, w1g, w2g, ffw1, ffw2,
                                  w1t, w2t, fw1t, fw2t, eidx, rs, cursor,
                                  bsum, bpre, stats, el2, bar);

  k_gather<<<12500, 256, 0, stream>>>(xbf, ea, rs, el2, hbf);

  k_megaB<<<GB, 256, 0, stream>>>(hbf, w1t, b1g, w2t, b2g, xbf, out, stats,
                                  bn1g, bn1b, fw1t, ffb1, fw2t, ffb2,
                                  bn2g, bn2b, bar);
}